// Round 3
// baseline (23232.925 us; speedup 1.0000x reference)
//
#include <hip/hip_runtime.h>
#include <math.h>

#define NB 256
#define NT 8192
#define NI 6
#define NU 64
#define NM 16
#define UNFOLDS 6
#define EPSF 1e-8f
#define LOG2E 1.44269504088896340736f

// LUT: sigma(y*ln2) = 1/(1+2^-y) sampled at y_k = (k-1024)/64, k=0..2048.
// Entry k holds {s_k, s_{k+1}-s_k}; lookup u = y*64+1024, clamped to [0, 2047.999].
#define LUT_N 2048
#define LUT_SCALE 64.0f
#define LUT_BIAS 1024.0f
#define LUT_MAXU 2047.999f

__device__ __forceinline__ float fexp2(float x) { return __builtin_amdgcn_exp2f(x); }
__device__ __forceinline__ float frcp(float x)  { return __builtin_amdgcn_rcpf(x); }
__device__ __forceinline__ float fmed3(float a, float b, float c) { return __builtin_amdgcn_fmed3f(a, b, c); }
__device__ __forceinline__ float ffract(float x) { return __builtin_amdgcn_fractf(x); }

// 8-lane all-reduce sum via DPP (lanes grouped 8-aligned within a wave).
template <int CTRL>
__device__ __forceinline__ float dpp_add(float x) {
  int t = __builtin_amdgcn_update_dpp(0, __float_as_int(x), CTRL, 0xF, 0xF, true);
  return x + __int_as_float(t);
}
__device__ __forceinline__ float red8(float x) {
  x = dpp_add<0xB1>(x);   // xor 1 (quad_perm [1,0,3,2])
  x = dpp_add<0x4E>(x);   // xor 2 (quad_perm [2,3,0,1])
  x = dpp_add<0x141>(x);  // xor 4 (row_half_mirror)
  return x;
}

// LDS-only barrier: drains lgkmcnt but NOT vmcnt (x-prefetch/output stores stay in flight).
__device__ __forceinline__ void lds_barrier() {
  asm volatile("s_waitcnt lgkmcnt(0)\n\ts_barrier" ::: "memory");
}

// One block = one batch row. 512 threads: thread = (j = tid>>3 dst unit, c = tid&7 src chunk).
__global__ __launch_bounds__(512, 2) void ltc_kernel(
    const float* __restrict__ x,
    const float* __restrict__ gleak, const float* __restrict__ vleak,
    const float* __restrict__ cm,
    const float* __restrict__ sigma, const float* __restrict__ mu,
    const float* __restrict__ w,     const float* __restrict__ erev,
    const float* __restrict__ ssigma, const float* __restrict__ smu,
    const float* __restrict__ sw_,    const float* __restrict__ serev,
    const float* __restrict__ iw, const float* __restrict__ ib,
    const float* __restrict__ ow_, const float* __restrict__ ob_,
    float* __restrict__ out)
{
  const int tid = threadIdx.x;
  const int b   = blockIdx.x;
  const int j   = tid >> 3;   // dst unit 0..63
  const int c   = tid & 7;    // src chunk 0..7
  const int i0  = c * 8;

  __shared__ float2 lut[LUT_N];
  __shared__ float vbuf[2][NU];

  // ---- build sigmoid LUT (once per 8192 steps; trivial cost) ----
  for (int e = tid; e < LUT_N; e += 512) {
    const float y0 = ((float)e - LUT_BIAS) * (1.0f / LUT_SCALE);
    const float y1 = ((float)(e + 1) - LUT_BIAS) * (1.0f / LUT_SCALE);
    const float s0 = 1.0f / (1.0f + exp2f(-y0));
    const float s1 = 1.0f / (1.0f + exp2f(-y1));
    lut[e] = make_float2(s0, s1 - s0);
  }

  // ---- preload + pre-transform recurrent weights ----
  // arg y = (v - mu)*sigma*log2e; LUT coord u = y*64 + 1024 = v*A1 + A0.
  float A1[8], A0[8], wv[8], we[8];
#pragma unroll
  for (int k = 0; k < 8; ++k) {
    const int idx = (i0 + k) * NU + j;
    const float sg = sigma[idx] * LOG2E;
    A1[k] = sg * LUT_SCALE;
    A0[k] = LUT_BIAS - mu[idx] * sg * LUT_SCALE;
    wv[k] = w[idx];
    we[k] = w[idx] * erev[idx];
  }
  // sensory synapse (exp/rcp path: arg range exceeds the LUT; runs once per step)
  float b1 = 0.f, b0 = 0.f, swv = 0.f, swe = 0.f;
  if (c < NI) {
    const int idx = c * NU + j;
    const float sg = ssigma[idx] * LOG2E;
    b1 = -sg * iw[c];
    b0 = sg * (smu[idx] - ib[c]);
    swv = sw_[idx];
    swe = swv * serev[idx];
  }
  const float gl   = gleak[j];
  const float glvl = gl * vleak[j];
  const float cmt  = cm[j] * (float)UNFOLDS;
  const float ow   = (j < NM) ? ow_[j] : 0.f;
  const float ob   = (j < NM) ? ob_[j] : 0.f;

  float v = 0.f;
  if (c == 0) vbuf[0][j] = 0.f;
  __syncthreads();

  const float* xp = x + (size_t)b * NT * NI + (c < NI ? c : 0);
  float* op = out + (size_t)b * NT * NM;

  float xv = xp[0];

  for (int t = 0; t < NT; ++t) {
    const int tn = (t + 1 < NT) ? (t + 1) : t;
    const float xnext = xp[tn * NI];

    // ---- sensory activations (constant across the 6 unfolds) ----
    const float es   = fexp2(fmaf(xv, b1, b0));
    const float ssig = frcp(1.f + es);
    const float num_s = red8(swe * ssig);
    const float den_s = red8(swv * ssig);
    const float num_base = glvl + num_s;
    const float den_base = cmt + gl + den_s + EPSF;

    // ---- fused semi-implicit Euler unfolds ----
#pragma unroll
    for (int u = 0; u < UNFOLDS; ++u) {
      const int p = u & 1;
      float vv[8];
      *(float4*)&vv[0] = *(const float4*)&vbuf[p][i0];
      *(float4*)&vv[4] = *(const float4*)&vbuf[p][i0 + 4];

      // sigmoid via LDS LUT gather + linear interp (zero trans ops)
      float s[8];
#pragma unroll
      for (int k = 0; k < 8; ++k) {
        const float uu = fmed3(fmaf(vv[k], A1[k], A0[k]), 0.0f, LUT_MAXU);
        const unsigned iu = (unsigned)uu;      // trunc == floor (uu >= 0)
        const float f = ffract(uu);
        const float2 e2 = lut[iu];
        s[k] = fmaf(f, e2.y, e2.x);
      }
      // even/odd split accumulation chains (shorter dep path)
      float an0 = 0.f, an1 = 0.f, ad0 = 0.f, ad1 = 0.f;
#pragma unroll
      for (int k = 0; k < 8; k += 2) {
        an0 = fmaf(we[k], s[k], an0);
        ad0 = fmaf(wv[k], s[k], ad0);
        an1 = fmaf(we[k + 1], s[k + 1], an1);
        ad1 = fmaf(wv[k + 1], s[k + 1], ad1);
      }
      const float an = red8(an0 + an1);
      const float ad = red8(ad0 + ad1);
      const float den = den_base + ad;
      const float num = fmaf(cmt, v, num_base) + an;
      v = num * frcp(den);
      if (c == 0) vbuf[p ^ 1][j] = v;
      lds_barrier();
    }

    // ---- map_outputs: first NM motor neurons ----
    if (c == 0 && j < NM) op[t * NM + j] = fmaf(v, ow, ob);
    xv = xnext;
  }
}

extern "C" void kernel_launch(void* const* d_in, const int* in_sizes, int n_in,
                              void* d_out, int out_size, void* d_ws, size_t ws_size,
                              hipStream_t stream) {
  (void)in_sizes; (void)n_in; (void)d_ws; (void)ws_size; (void)out_size;
  const float* x      = (const float*)d_in[0];
  const float* gleak  = (const float*)d_in[1];
  const float* vleak  = (const float*)d_in[2];
  const float* cm     = (const float*)d_in[3];
  const float* sigma  = (const float*)d_in[4];
  const float* mu     = (const float*)d_in[5];
  const float* w      = (const float*)d_in[6];
  const float* erev   = (const float*)d_in[7];
  const float* ssig   = (const float*)d_in[8];
  const float* smu    = (const float*)d_in[9];
  const float* sw     = (const float*)d_in[10];
  const float* serev  = (const float*)d_in[11];
  const float* iw     = (const float*)d_in[12];
  const float* ib     = (const float*)d_in[13];
  const float* ow     = (const float*)d_in[14];
  const float* ob     = (const float*)d_in[15];
  float* out = (float*)d_out;

  ltc_kernel<<<dim3(NB), dim3(512), 0, stream>>>(
      x, gleak, vleak, cm, sigma, mu, w, erev,
      ssig, smu, sw, serev, iw, ib, ow, ob, out);
}

// Round 4
// 20125.615 us; speedup vs baseline: 1.1544x; 1.1544x over previous
//
#include <hip/hip_runtime.h>

#define NB 256
#define NT 8192
#define NI 6
#define NU 64
#define NM 16
#define UNFOLDS 6
#define EPSF 1e-8f
#define LOG2E 1.44269504088896340736f

__device__ __forceinline__ float fexp2(float x) { return __builtin_amdgcn_exp2f(x); }
__device__ __forceinline__ float frcp(float x)  { return __builtin_amdgcn_rcpf(x); }

// 16-lane all-reduce sum via DPP (lanes grouped 16-aligned = one DPP row).
template <int CTRL>
__device__ __forceinline__ float dpp_add(float x) {
  int t = __builtin_amdgcn_update_dpp(0, __float_as_int(x), CTRL, 0xF, 0xF, true);
  return x + __int_as_float(t);
}
__device__ __forceinline__ float red16(float x) {
  x = dpp_add<0xB1>(x);   // xor 1 (quad_perm [1,0,3,2])
  x = dpp_add<0x4E>(x);   // xor 2 (quad_perm [2,3,0,1])
  x = dpp_add<0x141>(x);  // xor 4 (row_half_mirror: l -> (l&8)|(7-(l&7)))
  x = dpp_add<0x140>(x);  // xor 8 (row_mirror: l -> 15-(l&15) within row)
  return x;
}

// LDS-only barrier: drains lgkmcnt but NOT vmcnt (x-prefetch/output stores stay in flight).
__device__ __forceinline__ void lds_barrier() {
  asm volatile("s_waitcnt lgkmcnt(0)\n\ts_barrier" ::: "memory");
}

// One block = one batch row. 1024 threads: thread = (j = tid>>4 dst unit, c = tid&15 src chunk).
// Lane (j,c) accumulates src rows i in [4c, 4c+4); 16 waves/block = 4 waves/SIMD for latency hiding.
__global__ __launch_bounds__(1024, 4) void ltc_kernel(
    const float* __restrict__ x,
    const float* __restrict__ gleak, const float* __restrict__ vleak,
    const float* __restrict__ cm,
    const float* __restrict__ sigma, const float* __restrict__ mu,
    const float* __restrict__ w,     const float* __restrict__ erev,
    const float* __restrict__ ssigma, const float* __restrict__ smu,
    const float* __restrict__ sw_,    const float* __restrict__ serev,
    const float* __restrict__ iw, const float* __restrict__ ib,
    const float* __restrict__ ow_, const float* __restrict__ ob_,
    float* __restrict__ out)
{
  const int tid = threadIdx.x;
  const int b   = blockIdx.x;
  const int j   = tid >> 4;   // dst unit 0..63
  const int c   = tid & 15;   // src chunk 0..15
  const int i0  = c * 4;

  // ---- preload + pre-transform recurrent weights (once per 8192 steps) ----
  // sigmoid((v-mu)*sigma) = 1 / (1 + exp2(fma(v, a1, a0))),  a1=-sigma*log2e, a0=mu*sigma*log2e
  float a1[4], a0[4], wv[4], we[4];
#pragma unroll
  for (int k = 0; k < 4; ++k) {
    const int idx = (i0 + k) * NU + j;
    const float sg = sigma[idx] * LOG2E;
    a1[k] = -sg;
    a0[k] = mu[idx] * sg;
    wv[k] = w[idx];
    we[k] = w[idx] * erev[idx];
  }
  // sensory synapse: lane handles src i == c (c >= 6 contributes exactly 0)
  float b1 = 0.f, b0 = 0.f, swv = 0.f, swe = 0.f;
  if (c < NI) {
    const int idx = c * NU + j;
    const float sg = ssigma[idx] * LOG2E;
    b1 = -sg * iw[c];
    b0 = sg * (smu[idx] - ib[c]);
    swv = sw_[idx];
    swe = swv * serev[idx];
  }
  const float gl   = gleak[j];
  const float glvl = gl * vleak[j];
  const float cmt  = cm[j] * (float)UNFOLDS;   // cm / (elapsed/unfolds), elapsed=1
  const float ow   = (j < NM) ? ow_[j] : 0.f;
  const float ob   = (j < NM) ? ob_[j] : 0.f;

  __shared__ float vbuf[2][NU];
  float v = 0.f;                 // this lane's dst-unit state (replicated across its 16 chunk-lanes)
  if (c == 0) vbuf[0][j] = 0.f;
  __syncthreads();

  const float* xp = x + (size_t)b * NT * NI + (c < NI ? c : 0);
  float* op = out + (size_t)b * NT * NM;

  float xv = xp[0];

  for (int t = 0; t < NT; ++t) {
    // prefetch next timestep's input (hidden under ~6 unfolds of compute;
    // never drained early — barriers are LDS-only)
    const int tn = (t + 1 < NT) ? (t + 1) : t;
    const float xnext = xp[tn * NI];

    // ---- sensory activations (constant across the 6 unfolds) ----
    const float es   = fexp2(fmaf(xv, b1, b0));
    const float ssig = frcp(1.f + es);
    const float num_s = red16(swe * ssig);
    const float den_s = red16(swv * ssig);
    const float num_base = glvl + num_s;
    const float den_base = cmt + gl + den_s + EPSF;

    // ---- fused semi-implicit Euler unfolds (fully unrolled, static dbuf) ----
#pragma unroll
    for (int u = 0; u < UNFOLDS; ++u) {
      const int p = u & 1;
      float vv[4];
      *(float4*)&vv[0] = *(const float4*)&vbuf[p][i0];
      float an = 0.f, ad = 0.f;
#pragma unroll
      for (int k = 0; k < 4; ++k) {
        const float e = fexp2(fmaf(vv[k], a1[k], a0[k]));
        const float s = frcp(1.f + e);
        an = fmaf(we[k], s, an);
        ad = fmaf(wv[k], s, ad);
      }
      an = red16(an);
      ad = red16(ad);
      const float den = den_base + ad;
      const float num = fmaf(cmt, v, num_base) + an;
      v = num * frcp(den);
      if (c == 0) vbuf[p ^ 1][j] = v;
      lds_barrier();
    }

    // ---- map_outputs: first NM motor neurons ----
    if (c == 0 && j < NM) op[t * NM + j] = fmaf(v, ow, ob);
    xv = xnext;
  }
}

extern "C" void kernel_launch(void* const* d_in, const int* in_sizes, int n_in,
                              void* d_out, int out_size, void* d_ws, size_t ws_size,
                              hipStream_t stream) {
  (void)in_sizes; (void)n_in; (void)d_ws; (void)ws_size; (void)out_size;
  const float* x      = (const float*)d_in[0];
  const float* gleak  = (const float*)d_in[1];
  const float* vleak  = (const float*)d_in[2];
  const float* cm     = (const float*)d_in[3];
  const float* sigma  = (const float*)d_in[4];
  const float* mu     = (const float*)d_in[5];
  const float* w      = (const float*)d_in[6];
  const float* erev   = (const float*)d_in[7];
  const float* ssig   = (const float*)d_in[8];
  const float* smu    = (const float*)d_in[9];
  const float* sw     = (const float*)d_in[10];
  const float* serev  = (const float*)d_in[11];
  const float* iw     = (const float*)d_in[12];
  const float* ib     = (const float*)d_in[13];
  const float* ow     = (const float*)d_in[14];
  const float* ob     = (const float*)d_in[15];
  float* out = (float*)d_out;

  ltc_kernel<<<dim3(NB), dim3(1024), 0, stream>>>(
      x, gleak, vleak, cm, sigma, mu, w, erev,
      ssig, smu, sw, serev, iw, ib, ow, ob, out);
}

// Round 5
// 16379.962 us; speedup vs baseline: 1.4184x; 1.2287x over previous
//
#include <hip/hip_runtime.h>

#define NB 256
#define NT 8192
#define NI 6
#define NU 64
#define NM 16
#define UNFOLDS 6
#define EPSF 1e-8f
#define LOG2E 1.44269504088896340736f

typedef float v2f __attribute__((ext_vector_type(2)));

__device__ __forceinline__ float fexp2(float x) { return __builtin_amdgcn_exp2f(x); }
__device__ __forceinline__ float frcp(float x)  { return __builtin_amdgcn_rcpf(x); }

// 8-lane all-reduce sum via DPP (lanes grouped 8-aligned within a wave).
template <int CTRL>
__device__ __forceinline__ float dpp_add(float x) {
  int t = __builtin_amdgcn_update_dpp(0, __float_as_int(x), CTRL, 0xF, 0xF, true);
  return x + __int_as_float(t);
}
__device__ __forceinline__ float red8(float x) {
  x = dpp_add<0xB1>(x);   // xor 1 (quad_perm [1,0,3,2])
  x = dpp_add<0x4E>(x);   // xor 2 (quad_perm [2,3,0,1])
  x = dpp_add<0x141>(x);  // xor 7 -> other quad (row_half_mirror), quad-uniform by then
  return x;
}

// LDS-only barrier: drains lgkmcnt but NOT vmcnt (x-prefetch/output stores stay in flight).
__device__ __forceinline__ void lds_barrier() {
  asm volatile("s_waitcnt lgkmcnt(0)\n\ts_barrier" ::: "memory");
}

// One block = one batch row. 512 threads: thread = (j = tid>>3 dst unit, c = tid&7 src chunk).
// Per lane: 8 synapses, processed as 4 pairs with one shared rcp per pair; the
// {num,den} accumulators travel packed in a v2f so the FMAs hit v_pk_fma_f32.
__global__ __launch_bounds__(512, 2) void ltc_kernel(
    const float* __restrict__ x,
    const float* __restrict__ gleak, const float* __restrict__ vleak,
    const float* __restrict__ cm,
    const float* __restrict__ sigma, const float* __restrict__ mu,
    const float* __restrict__ w,     const float* __restrict__ erev,
    const float* __restrict__ ssigma, const float* __restrict__ smu,
    const float* __restrict__ sw_,    const float* __restrict__ serev,
    const float* __restrict__ iw, const float* __restrict__ ib,
    const float* __restrict__ ow_, const float* __restrict__ ob_,
    float* __restrict__ out)
{
  const int tid = threadIdx.x;
  const int b   = blockIdx.x;
  const int j   = tid >> 3;   // dst unit 0..63
  const int c   = tid & 7;    // src chunk 0..7
  const int i0  = c * 8;

  // ---- preload + pre-transform recurrent weights (once per 8192 steps) ----
  // sigmoid((v-mu)*sigma) = 1/(1+exp2(y)), y = fma(v, -sg, mu*sg), sg = sigma*log2e.
  // Packed pairs: a1p[q]/a0p[q] hold synapses k=2q,2q+1; wq[k] = {w*erev, w}.
  v2f a1p[4], a0p[4], wq[8];
#pragma unroll
  for (int k = 0; k < 8; ++k) {
    const int idx = (i0 + k) * NU + j;
    const float sg = sigma[idx] * LOG2E;
    a1p[k >> 1][k & 1] = -sg;
    a0p[k >> 1][k & 1] = mu[idx] * sg;
    const float wvk = w[idx];
    wq[k] = (v2f){wvk * erev[idx], wvk};
  }
  // sensory synapse: lane handles src i == c (c >= 6 contributes exactly 0)
  float b1 = 0.f, b0 = 0.f, swv = 0.f, swe = 0.f;
  if (c < NI) {
    const int idx = c * NU + j;
    const float sg = ssigma[idx] * LOG2E;
    b1 = -sg * iw[c];
    b0 = sg * (smu[idx] - ib[c]);
    swv = sw_[idx];
    swe = swv * serev[idx];
  }
  const float gl   = gleak[j];
  const float glvl = gl * vleak[j];
  const float cmt  = cm[j] * (float)UNFOLDS;   // cm / (elapsed/unfolds), elapsed=1
  const float ow   = (j < NM) ? ow_[j] : 0.f;
  const float ob   = (j < NM) ? ob_[j] : 0.f;

  __shared__ float vbuf[2][NU];
  float v = 0.f;                 // this lane's dst-unit state (replicated across its 8 chunk-lanes)
  if (c == 0) vbuf[0][j] = 0.f;
  __syncthreads();

  const float* xp = x + (size_t)b * NT * NI + (c < NI ? c : 0);
  float* op = out + (size_t)b * NT * NM;

  float xv = xp[0];

  for (int t = 0; t < NT; ++t) {
    // prefetch next timestep's input (hidden under ~6 unfolds of compute;
    // never drained early — barriers are LDS-only)
    const int tn = (t + 1 < NT) ? (t + 1) : t;
    const float xnext = xp[tn * NI];

    // ---- sensory activations (constant across the 6 unfolds) ----
    const float es   = fexp2(fmaf(xv, b1, b0));
    const float ssig = frcp(1.f + es);
    const float num_s = red8(swe * ssig);
    const float den_s = red8(swv * ssig);
    const float num_base = glvl + num_s;
    const float den_base = cmt + gl + den_s + EPSF;

    // ---- fused semi-implicit Euler unfolds (fully unrolled, static dbuf) ----
#pragma unroll
    for (int u = 0; u < UNFOLDS; ++u) {
      const int p = u & 1;
      float4 f0 = *(const float4*)&vbuf[p][i0];
      float4 f1 = *(const float4*)&vbuf[p][i0 + 4];
      v2f vp[4] = { {f0.x, f0.y}, {f0.z, f0.w}, {f1.x, f1.y}, {f1.z, f1.w} };

      // two independent packed accumulator chains: acc = {num-part, den-part}
      v2f accA = (v2f){0.f, 0.f}, accB = (v2f){0.f, 0.f};
#pragma unroll
      for (int q = 0; q < 4; ++q) {
        const v2f y = vp[q] * a1p[q] + a0p[q];        // v_pk_fma_f32
        const float e0 = fexp2(y.x);
        const float e1 = fexp2(y.y);
        const float d0 = 1.f + e0;
        const float d1 = 1.f + e1;
        const float r  = frcp(d0 * d1);               // one rcp per 2 sigmoids
        // s0 = d1*r, s1 = d0*r; acc += {we,wv}_0*s0 + {we,wv}_1*s1
        v2f tq = wq[2 * q] * d1 + wq[2 * q + 1] * d0; // pk_mul + pk_fma
        if (q & 1) accB += tq * r; else accA += tq * r;
      }
      const v2f acc = accA + accB;
      const float an = red8(acc.x);
      const float ad = red8(acc.y);
      const float den = den_base + ad;
      const float num = fmaf(cmt, v, num_base) + an;
      v = num * frcp(den);
      if (c == 0) vbuf[p ^ 1][j] = v;
      lds_barrier();
    }

    // ---- map_outputs: first NM motor neurons ----
    if (c == 0 && j < NM) op[t * NM + j] = fmaf(v, ow, ob);
    xv = xnext;
  }
}

extern "C" void kernel_launch(void* const* d_in, const int* in_sizes, int n_in,
                              void* d_out, int out_size, void* d_ws, size_t ws_size,
                              hipStream_t stream) {
  (void)in_sizes; (void)n_in; (void)d_ws; (void)ws_size; (void)out_size;
  const float* x      = (const float*)d_in[0];
  const float* gleak  = (const float*)d_in[1];
  const float* vleak  = (const float*)d_in[2];
  const float* cm     = (const float*)d_in[3];
  const float* sigma  = (const float*)d_in[4];
  const float* mu     = (const float*)d_in[5];
  const float* w      = (const float*)d_in[6];
  const float* erev   = (const float*)d_in[7];
  const float* ssig   = (const float*)d_in[8];
  const float* smu    = (const float*)d_in[9];
  const float* sw     = (const float*)d_in[10];
  const float* serev  = (const float*)d_in[11];
  const float* iw     = (const float*)d_in[12];
  const float* ib     = (const float*)d_in[13];
  const float* ow     = (const float*)d_in[14];
  const float* ob     = (const float*)d_in[15];
  float* out = (float*)d_out;

  ltc_kernel<<<dim3(NB), dim3(512), 0, stream>>>(
      x, gleak, vleak, cm, sigma, mu, w, erev,
      ssig, smu, sw, serev, iw, ib, ow, ob, out);
}